// Round 1
// baseline (292.419 us; speedup 1.0000x reference)
//
#include <hip/hip_runtime.h>
#include <hip/hip_fp16.h>

#define TT 512
#define BB 4096

__device__ __forceinline__ const float* sel4(int g, const float* a, const float* b,
                                             const float* c, const float* d) {
    return g == 0 ? a : (g == 1 ? b : (g == 2 ? c : d));
}

__device__ __forceinline__ float sigmoid_fast(float x) {
    float e = __expf(-x);
    return __builtin_amdgcn_rcpf(1.0f + e);
}
__device__ __forceinline__ float tanh_fast(float x) {
    float e = __expf(-2.0f * x);
    return fmaf(2.0f, __builtin_amdgcn_rcpf(1.0f + e), -1.0f);
}

// ---------------- Phase 1: Ax[t*B+b][16] = x @ Wx + (b + theta), stored fp16 ----------------
__global__ __launch_bounds__(256) void qlstm_pre(
    const float* __restrict__ x,
    const float* __restrict__ Wf, const float* __restrict__ bf, const float* __restrict__ thf,
    const float* __restrict__ Wi, const float* __restrict__ bi, const float* __restrict__ thi,
    const float* __restrict__ Wu, const float* __restrict__ bu, const float* __restrict__ thu,
    const float* __restrict__ Wo, const float* __restrict__ bo, const float* __restrict__ tho,
    __half* __restrict__ Ax)
{
    __shared__ float4 Wl[32][4];   // Wl[j][q] = cols 4q..4q+3 of concatenated Wx at input j
    __shared__ float4 bias4[4];
    int tid = threadIdx.x;
    for (int idx = tid; idx < 512; idx += 256) {
        int j = idx >> 4, c = idx & 15, g = c >> 2, w = c & 3;
        ((float*)Wl)[idx] = sel4(g, Wf, Wi, Wu, Wo)[j * 4 + w];
    }
    if (tid < 16) {
        int g = tid >> 2, w = tid & 3;
        ((float*)bias4)[tid] = sel4(g, bf, bi, bu, bo)[w] + sel4(g, thf, thi, thu, tho)[w];
    }
    __syncthreads();

    size_t r = (size_t)blockIdx.x * 256 + tid;          // row in [0, T*B)
    const float4* xr = (const float4*)(x + r * 32);
    float4 xv[8];
#pragma unroll
    for (int k = 0; k < 8; ++k) xv[k] = xr[k];

    float4 acc[4];
#pragma unroll
    for (int q = 0; q < 4; ++q) acc[q] = bias4[q];

#pragma unroll
    for (int j = 0; j < 32; ++j) {
        float xj = ((const float*)xv)[j];
#pragma unroll
        for (int q = 0; q < 4; ++q) {
            float4 wv = Wl[j][q];
            acc[q].x = fmaf(xj, wv.x, acc[q].x);
            acc[q].y = fmaf(xj, wv.y, acc[q].y);
            acc[q].z = fmaf(xj, wv.z, acc[q].z);
            acc[q].w = fmaf(xj, wv.w, acc[q].w);
        }
    }

    union { __half2 h2; unsigned u; } cv;
    uint4 s0, s1;
    cv.h2 = __floats2half2_rn(acc[0].x, acc[0].y); s0.x = cv.u;
    cv.h2 = __floats2half2_rn(acc[0].z, acc[0].w); s0.y = cv.u;
    cv.h2 = __floats2half2_rn(acc[1].x, acc[1].y); s0.z = cv.u;
    cv.h2 = __floats2half2_rn(acc[1].z, acc[1].w); s0.w = cv.u;
    cv.h2 = __floats2half2_rn(acc[2].x, acc[2].y); s1.x = cv.u;
    cv.h2 = __floats2half2_rn(acc[2].z, acc[2].w); s1.y = cv.u;
    cv.h2 = __floats2half2_rn(acc[3].x, acc[3].y); s1.z = cv.u;
    cv.h2 = __floats2half2_rn(acc[3].z, acc[3].w); s1.w = cv.u;
    uint4* Ap = (uint4*)Ax + r * 2;
    Ap[0] = s0; Ap[1] = s1;
}

// ---------------- Phase 2: sequential scan, 4 lanes per batch row (lane = gate) -------------
template<int FUSED>
__global__ __launch_bounds__(64) void qlstm_scan(
    const __half* __restrict__ Ax, const float* __restrict__ x,
    const float* __restrict__ Wf, const float* __restrict__ bf, const float* __restrict__ thf,
    const float* __restrict__ Wi, const float* __restrict__ bi, const float* __restrict__ thi,
    const float* __restrict__ Wu, const float* __restrict__ bu, const float* __restrict__ thu,
    const float* __restrict__ Wo, const float* __restrict__ bo, const float* __restrict__ tho,
    float* __restrict__ out)
{
    int lane = threadIdx.x;                 // 0..63, one wave per block
    int gid  = blockIdx.x * 64 + lane;      // 0..16383
    int b    = gid >> 2;                    // batch row
    int g    = lane & 3;                    // gate: 0=f 1=i 2=u 3=o
    int base4 = lane & ~3;

    const float* Wg = sel4(g, Wf, Wi, Wu, Wo);
    float wh[4][4];                         // recurrent weights Wh[j][w] = Wg[(32+j)*4+w]
#pragma unroll
    for (int j = 0; j < 4; ++j)
#pragma unroll
        for (int w = 0; w < 4; ++w)
            wh[j][w] = Wg[(32 + j) * 4 + w];

    __shared__ float4 Wl[32][4];
    float bias[4] = {0, 0, 0, 0};
    if (FUSED) {
        for (int idx = lane; idx < 512; idx += 64) {
            int j = idx >> 4, c = idx & 15, gg = c >> 2, w = c & 3;
            ((float*)Wl)[idx] = sel4(gg, Wf, Wi, Wu, Wo)[j * 4 + w];
        }
#pragma unroll
        for (int w = 0; w < 4; ++w)
            bias[w] = sel4(g, bf, bi, bu, bo)[w] + sel4(g, thf, thi, thu, tho)[w];
        __syncthreads();
    }

    float hx[4] = {0, 0, 0, 0}, cx[4] = {0, 0, 0, 0};

    const uint2* Axp = (const uint2*)Ax + (size_t)b * 4 + g;  // +t*16384 per step
    const float4* xp = (const float4*)x + (size_t)b * 8;      // +t*32768 per step
    uint2 nxt = {0, 0};
    float4 xnxt[8];
    if (!FUSED) {
        nxt = Axp[0];
    } else {
#pragma unroll
        for (int k = 0; k < 8; ++k) xnxt[k] = xp[k];
    }

    for (int t = 0; t < TT; ++t) {
        float ax[4];
        if (!FUSED) {
            uint2 cur = nxt;
            if (t + 1 < TT) nxt = Axp[(size_t)(t + 1) * (BB * 4)];
            __half2 p0 = *reinterpret_cast<const __half2*>(&cur.x);
            __half2 p1 = *reinterpret_cast<const __half2*>(&cur.y);
            float2 f0 = __half22float2(p0), f1 = __half22float2(p1);
            ax[0] = f0.x; ax[1] = f0.y; ax[2] = f1.x; ax[3] = f1.y;
        } else {
            float4 xc[8];
#pragma unroll
            for (int k = 0; k < 8; ++k) xc[k] = xnxt[k];
            if (t + 1 < TT) {
#pragma unroll
                for (int k = 0; k < 8; ++k) xnxt[k] = xp[(size_t)(t + 1) * (BB * 8) + k];
            }
#pragma unroll
            for (int w = 0; w < 4; ++w) ax[w] = bias[w];
#pragma unroll
            for (int j = 0; j < 32; ++j) {
                float xj = ((const float*)xc)[j];
                float4 wv = Wl[j][g];
                ax[0] = fmaf(xj, wv.x, ax[0]);
                ax[1] = fmaf(xj, wv.y, ax[1]);
                ax[2] = fmaf(xj, wv.z, ax[2]);
                ax[3] = fmaf(xj, wv.w, ax[3]);
            }
        }

        // angles -> cos
        float C[4];
#pragma unroll
        for (int w = 0; w < 4; ++w) {
            float a = ax[w];
            a = fmaf(hx[0], wh[0][w], a);
            a = fmaf(hx[1], wh[1][w], a);
            a = fmaf(hx[2], wh[2][w], a);
            a = fmaf(hx[3], wh[3][w], a);
            C[w] = __cosf(a);
        }
        // z via XOR-subset products (closed form of CNOT ring + PauliZ)
        float t12 = C[1] * C[2];
        float z[4];
        z[1] = C[0] * C[1];
        z[2] = C[0] * t12;
        z[0] = t12 * C[3];
        z[3] = z[2] * C[3];

        bool isU = (g == 2);
        float act[4];
#pragma unroll
        for (int w = 0; w < 4; ++w) {
            float zz = isU ? z[w] + z[w] : z[w];
            float y = sigmoid_fast(zz);                 // tanh(x) = 2*sigmoid(2x)-1
            act[w] = isU ? fmaf(2.0f, y, -1.0f) : y;
        }

        // quad gather: f,i,u,o for each component w
        float hxn[4], cxn[4];
#pragma unroll
        for (int w = 0; w < 4; ++w) {
            float fw = __shfl(act[w], base4 + 0, 64);
            float iw = __shfl(act[w], base4 + 1, 64);
            float uw = __shfl(act[w], base4 + 2, 64);
            float ow = __shfl(act[w], base4 + 3, 64);
            float c2 = fmaf(fw, cx[w], iw * uw);
            float th = tanh_fast(c2);
            cxn[w] = c2;
            hxn[w] = ow * th;
        }
#pragma unroll
        for (int w = 0; w < 4; ++w) { hx[w] = hxn[w]; cx[w] = cxn[w]; }

        float o01 = (g & 1) ? hx[1] : hx[0];
        float o23 = (g & 1) ? hx[3] : hx[2];
        out[(size_t)t * 16384 + gid] = (g & 2) ? o23 : o01;
    }

    // final (hx, cx)
    {
        float o01 = (g & 1) ? hx[1] : hx[0];
        float o23 = (g & 1) ? hx[3] : hx[2];
        out[(size_t)TT * 16384 + gid] = (g & 2) ? o23 : o01;
        float c01 = (g & 1) ? cx[1] : cx[0];
        float c23 = (g & 1) ? cx[3] : cx[2];
        out[(size_t)TT * 16384 + 16384 + gid] = (g & 2) ? c23 : c01;
    }
}

extern "C" void kernel_launch(void* const* d_in, const int* in_sizes, int n_in,
                              void* d_out, int out_size, void* d_ws, size_t ws_size,
                              hipStream_t stream) {
    const float* x   = (const float*)d_in[0];
    const float* Wf  = (const float*)d_in[1];
    const float* bf  = (const float*)d_in[2];
    const float* thf = (const float*)d_in[3];
    const float* Wi  = (const float*)d_in[4];
    const float* bi  = (const float*)d_in[5];
    const float* thi = (const float*)d_in[6];
    const float* Wu  = (const float*)d_in[7];
    const float* bu  = (const float*)d_in[8];
    const float* thu = (const float*)d_in[9];
    const float* Wo  = (const float*)d_in[10];
    const float* bo  = (const float*)d_in[11];
    const float* tho = (const float*)d_in[12];
    float* out = (float*)d_out;

    size_t need = (size_t)TT * BB * 16 * sizeof(__half);   // 64 MB
    if (ws_size >= need) {
        __half* Ax = (__half*)d_ws;
        qlstm_pre<<<(TT * BB) / 256, 256, 0, stream>>>(
            x, Wf, bf, thf, Wi, bi, thi, Wu, bu, thu, Wo, bo, tho, Ax);
        qlstm_scan<0><<<(BB * 4) / 64, 64, 0, stream>>>(
            Ax, x, Wf, bf, thf, Wi, bi, thi, Wu, bu, thu, Wo, bo, tho, out);
    } else {
        qlstm_scan<1><<<(BB * 4) / 64, 64, 0, stream>>>(
            nullptr, x, Wf, bf, thf, Wi, bi, thi, Wu, bu, thu, Wo, bo, tho, out);
    }
}

// Round 2
// 223.637 us; speedup vs baseline: 1.3076x; 1.3076x over previous
//
#include <hip/hip_runtime.h>
#include <hip/hip_fp16.h>

#define TT 512
#define BB 4096
#define PD 8   // prefetch depth (must divide TT; loop unrolled by PD for static buf idx)

__device__ __forceinline__ const float* sel4(int g, const float* a, const float* b,
                                             const float* c, const float* d) {
    return g == 0 ? a : (g == 1 ? b : (g == 2 ? c : d));
}

__device__ __forceinline__ float sigmoid_fast(float x) {
    float e = __expf(-x);
    return __builtin_amdgcn_rcpf(1.0f + e);
}
__device__ __forceinline__ float tanh_fast(float x) {
    float e = __expf(-2.0f * x);
    return fmaf(2.0f, __builtin_amdgcn_rcpf(1.0f + e), -1.0f);
}

// DPP quad broadcast: every lane gets value from lane (quad_base + K) of its quad.
template<int CTRL>
__device__ __forceinline__ float quad_bcast(float v) {
    int i = __builtin_amdgcn_mov_dpp(__float_as_int(v), CTRL, 0xf, 0xf, true);
    return __int_as_float(i);
}

// ---------------- Phase 1: Ax[t*B+b][16] = x @ Wx + (b + theta), stored fp16 ----------------
__global__ __launch_bounds__(256) void qlstm_pre(
    const float* __restrict__ x,
    const float* __restrict__ Wf, const float* __restrict__ bf, const float* __restrict__ thf,
    const float* __restrict__ Wi, const float* __restrict__ bi, const float* __restrict__ thi,
    const float* __restrict__ Wu, const float* __restrict__ bu, const float* __restrict__ thu,
    const float* __restrict__ Wo, const float* __restrict__ bo, const float* __restrict__ tho,
    __half* __restrict__ Ax)
{
    __shared__ float4 Wl[32][4];   // Wl[j][q] = cols 4q..4q+3 of concatenated Wx at input j
    __shared__ float4 bias4[4];
    int tid = threadIdx.x;
    for (int idx = tid; idx < 512; idx += 256) {
        int j = idx >> 4, c = idx & 15, g = c >> 2, w = c & 3;
        ((float*)Wl)[idx] = sel4(g, Wf, Wi, Wu, Wo)[j * 4 + w];
    }
    if (tid < 16) {
        int g = tid >> 2, w = tid & 3;
        ((float*)bias4)[tid] = sel4(g, bf, bi, bu, bo)[w] + sel4(g, thf, thi, thu, tho)[w];
    }
    __syncthreads();

    size_t r = (size_t)blockIdx.x * 256 + tid;          // row in [0, T*B)
    const float4* xr = (const float4*)(x + r * 32);
    float4 xv[8];
#pragma unroll
    for (int k = 0; k < 8; ++k) xv[k] = xr[k];

    float4 acc[4];
#pragma unroll
    for (int q = 0; q < 4; ++q) acc[q] = bias4[q];

#pragma unroll
    for (int j = 0; j < 32; ++j) {
        float xj = ((const float*)xv)[j];
#pragma unroll
        for (int q = 0; q < 4; ++q) {
            float4 wv = Wl[j][q];
            acc[q].x = fmaf(xj, wv.x, acc[q].x);
            acc[q].y = fmaf(xj, wv.y, acc[q].y);
            acc[q].z = fmaf(xj, wv.z, acc[q].z);
            acc[q].w = fmaf(xj, wv.w, acc[q].w);
        }
    }

    union { __half2 h2; unsigned u; } cv;
    uint4 s0, s1;
    cv.h2 = __floats2half2_rn(acc[0].x, acc[0].y); s0.x = cv.u;
    cv.h2 = __floats2half2_rn(acc[0].z, acc[0].w); s0.y = cv.u;
    cv.h2 = __floats2half2_rn(acc[1].x, acc[1].y); s0.z = cv.u;
    cv.h2 = __floats2half2_rn(acc[1].z, acc[1].w); s0.w = cv.u;
    cv.h2 = __floats2half2_rn(acc[2].x, acc[2].y); s1.x = cv.u;
    cv.h2 = __floats2half2_rn(acc[2].z, acc[2].w); s1.y = cv.u;
    cv.h2 = __floats2half2_rn(acc[3].x, acc[3].y); s1.z = cv.u;
    cv.h2 = __floats2half2_rn(acc[3].z, acc[3].w); s1.w = cv.u;
    uint4* Ap = (uint4*)Ax + r * 2;
    Ap[0] = s0; Ap[1] = s1;
}

// ---------------- Phase 2: sequential scan, 4 lanes per batch row (lane = gate) -------------
template<int FUSED>
__global__ __launch_bounds__(64) void qlstm_scan(
    const __half* __restrict__ Ax, const float* __restrict__ x,
    const float* __restrict__ Wf, const float* __restrict__ bf, const float* __restrict__ thf,
    const float* __restrict__ Wi, const float* __restrict__ bi, const float* __restrict__ thi,
    const float* __restrict__ Wu, const float* __restrict__ bu, const float* __restrict__ thu,
    const float* __restrict__ Wo, const float* __restrict__ bo, const float* __restrict__ tho,
    float* __restrict__ out)
{
    int lane = threadIdx.x;                 // 0..63, one wave per block
    int gid  = blockIdx.x * 64 + lane;      // 0..16383
    int b    = gid >> 2;                    // batch row
    int g    = lane & 3;                    // gate: 0=f 1=i 2=u 3=o

    const float* Wg = sel4(g, Wf, Wi, Wu, Wo);
    float wh[4][4];                         // recurrent weights Wh[j][w] = Wg[(32+j)*4+w]
#pragma unroll
    for (int j = 0; j < 4; ++j)
#pragma unroll
        for (int w = 0; w < 4; ++w)
            wh[j][w] = Wg[(32 + j) * 4 + w];

    __shared__ float4 Wl[32][4];
    float bias[4] = {0, 0, 0, 0};
    if (FUSED) {
        for (int idx = lane; idx < 512; idx += 64) {
            int j = idx >> 4, c = idx & 15, gg = c >> 2, w = c & 3;
            ((float*)Wl)[idx] = sel4(gg, Wf, Wi, Wu, Wo)[j * 4 + w];
        }
#pragma unroll
        for (int w = 0; w < 4; ++w)
            bias[w] = sel4(g, bf, bi, bu, bo)[w] + sel4(g, thf, thi, thu, tho)[w];
        __syncthreads();
    }

    float hx[4] = {0, 0, 0, 0}, cx[4] = {0, 0, 0, 0};

    const uint2* Axp = (const uint2*)Ax + (size_t)b * 4 + g;  // +t*16384 per step
    const float4* xp = (const float4*)x + (size_t)b * 8;      // +t*32768 per step

    uint2 buf[PD];
    float4 xnxt[8];
    if (!FUSED) {
#pragma unroll
        for (int k = 0; k < PD; ++k) buf[k] = Axp[(size_t)k * (BB * 4)];
    } else {
#pragma unroll
        for (int k = 0; k < 8; ++k) xnxt[k] = xp[k];
    }

#pragma unroll PD
    for (int t = 0; t < TT; ++t) {
        float ax[4];
        if (!FUSED) {
            uint2 cur = buf[t % PD];                       // static after unroll-by-PD
            if (t + PD < TT) buf[t % PD] = Axp[(size_t)(t + PD) * (BB * 4)];
            __half2 p0 = *reinterpret_cast<const __half2*>(&cur.x);
            __half2 p1 = *reinterpret_cast<const __half2*>(&cur.y);
            float2 f0 = __half22float2(p0), f1 = __half22float2(p1);
            ax[0] = f0.x; ax[1] = f0.y; ax[2] = f1.x; ax[3] = f1.y;
        } else {
            float4 xc[8];
#pragma unroll
            for (int k = 0; k < 8; ++k) xc[k] = xnxt[k];
            if (t + 1 < TT) {
#pragma unroll
                for (int k = 0; k < 8; ++k) xnxt[k] = xp[(size_t)(t + 1) * (BB * 8) + k];
            }
#pragma unroll
            for (int w = 0; w < 4; ++w) ax[w] = bias[w];
#pragma unroll
            for (int j = 0; j < 32; ++j) {
                float xj = ((const float*)xc)[j];
                float4 wv = Wl[j][g];
                ax[0] = fmaf(xj, wv.x, ax[0]);
                ax[1] = fmaf(xj, wv.y, ax[1]);
                ax[2] = fmaf(xj, wv.z, ax[2]);
                ax[3] = fmaf(xj, wv.w, ax[3]);
            }
        }

        // angles -> cos
        float C[4];
#pragma unroll
        for (int w = 0; w < 4; ++w) {
            float a = ax[w];
            a = fmaf(hx[0], wh[0][w], a);
            a = fmaf(hx[1], wh[1][w], a);
            a = fmaf(hx[2], wh[2][w], a);
            a = fmaf(hx[3], wh[3][w], a);
            C[w] = __cosf(a);
        }
        // z via XOR-subset products (closed form of CNOT ring + PauliZ)
        float t12 = C[1] * C[2];
        float z[4];
        z[1] = C[0] * C[1];
        z[2] = C[0] * t12;
        z[0] = t12 * C[3];
        z[3] = z[2] * C[3];

        bool isU = (g == 2);
        float act[4];
#pragma unroll
        for (int w = 0; w < 4; ++w) {
            float zz = isU ? z[w] + z[w] : z[w];
            float y = sigmoid_fast(zz);                 // tanh(x) = 2*sigmoid(2x)-1
            act[w] = isU ? fmaf(2.0f, y, -1.0f) : y;
        }

        // quad gather via DPP quad_perm broadcasts (VALU-speed, no LDS)
        float hxn[4], cxn[4];
#pragma unroll
        for (int w = 0; w < 4; ++w) {
            float fw = quad_bcast<0x00>(act[w]);   // lane base4+0
            float iw = quad_bcast<0x55>(act[w]);   // lane base4+1
            float uw = quad_bcast<0xAA>(act[w]);   // lane base4+2
            float ow = quad_bcast<0xFF>(act[w]);   // lane base4+3
            float c2 = fmaf(fw, cx[w], iw * uw);
            float th = tanh_fast(c2);
            cxn[w] = c2;
            hxn[w] = ow * th;
        }
#pragma unroll
        for (int w = 0; w < 4; ++w) { hx[w] = hxn[w]; cx[w] = cxn[w]; }

        float o01 = (g & 1) ? hx[1] : hx[0];
        float o23 = (g & 1) ? hx[3] : hx[2];
        out[(size_t)t * 16384 + gid] = (g & 2) ? o23 : o01;
    }

    // final (hx, cx)
    {
        float o01 = (g & 1) ? hx[1] : hx[0];
        float o23 = (g & 1) ? hx[3] : hx[2];
        out[(size_t)TT * 16384 + gid] = (g & 2) ? o23 : o01;
        float c01 = (g & 1) ? cx[1] : cx[0];
        float c23 = (g & 1) ? cx[3] : cx[2];
        out[(size_t)TT * 16384 + 16384 + gid] = (g & 2) ? c23 : c01;
    }
}

extern "C" void kernel_launch(void* const* d_in, const int* in_sizes, int n_in,
                              void* d_out, int out_size, void* d_ws, size_t ws_size,
                              hipStream_t stream) {
    const float* x   = (const float*)d_in[0];
    const float* Wf  = (const float*)d_in[1];
    const float* bf  = (const float*)d_in[2];
    const float* thf = (const float*)d_in[3];
    const float* Wi  = (const float*)d_in[4];
    const float* bi  = (const float*)d_in[5];
    const float* thi = (const float*)d_in[6];
    const float* Wu  = (const float*)d_in[7];
    const float* bu  = (const float*)d_in[8];
    const float* thu = (const float*)d_in[9];
    const float* Wo  = (const float*)d_in[10];
    const float* bo  = (const float*)d_in[11];
    const float* tho = (const float*)d_in[12];
    float* out = (float*)d_out;

    size_t need = (size_t)TT * BB * 16 * sizeof(__half);   // 64 MB
    if (ws_size >= need) {
        __half* Ax = (__half*)d_ws;
        qlstm_pre<<<(TT * BB) / 256, 256, 0, stream>>>(
            x, Wf, bf, thf, Wi, bi, thi, Wu, bu, thu, Wo, bo, tho, Ax);
        qlstm_scan<0><<<(BB * 4) / 64, 64, 0, stream>>>(
            Ax, x, Wf, bf, thf, Wi, bi, thi, Wu, bu, thu, Wo, bo, tho, out);
    } else {
        qlstm_scan<1><<<(BB * 4) / 64, 64, 0, stream>>>(
            nullptr, x, Wf, bf, thf, Wi, bi, thi, Wu, bu, thu, Wo, bo, tho, out);
    }
}

// Round 3
// 223.157 us; speedup vs baseline: 1.3104x; 1.0022x over previous
//
#include <hip/hip_runtime.h>
#include <hip/hip_fp16.h>

#define TT 512
#define BB 4096
#define PD 16  // prefetch depth (must divide TT; loop unrolled by PD for static buf idx)

__device__ __forceinline__ const float* sel4(int g, const float* a, const float* b,
                                             const float* c, const float* d) {
    return g == 0 ? a : (g == 1 ? b : (g == 2 ? c : d));
}

__device__ __forceinline__ float sigmoid_fast(float x) {
    float e = __expf(-x);
    return __builtin_amdgcn_rcpf(1.0f + e);
}
__device__ __forceinline__ float tanh_fast(float x) {
    float e = __expf(-2.0f * x);
    return fmaf(2.0f, __builtin_amdgcn_rcpf(1.0f + e), -1.0f);
}

// DPP quad broadcast: every lane gets value from lane (quad_base + K) of its quad.
template<int CTRL>
__device__ __forceinline__ float quad_bcast(float v) {
    int i = __builtin_amdgcn_mov_dpp(__float_as_int(v), CTRL, 0xf, 0xf, true);
    return __int_as_float(i);
}

// ---------------- Phase 1: Ax[t*B+b][16] = x @ Wx + (b + theta), stored fp16 ----------------
__global__ __launch_bounds__(256) void qlstm_pre(
    const float* __restrict__ x,
    const float* __restrict__ Wf, const float* __restrict__ bf, const float* __restrict__ thf,
    const float* __restrict__ Wi, const float* __restrict__ bi, const float* __restrict__ thi,
    const float* __restrict__ Wu, const float* __restrict__ bu, const float* __restrict__ thu,
    const float* __restrict__ Wo, const float* __restrict__ bo, const float* __restrict__ tho,
    __half* __restrict__ Ax)
{
    __shared__ float4 Wl[32][4];   // Wl[j][q] = cols 4q..4q+3 of concatenated Wx at input j
    __shared__ float4 bias4[4];
    int tid = threadIdx.x;
    for (int idx = tid; idx < 512; idx += 256) {
        int j = idx >> 4, c = idx & 15, g = c >> 2, w = c & 3;
        ((float*)Wl)[idx] = sel4(g, Wf, Wi, Wu, Wo)[j * 4 + w];
    }
    if (tid < 16) {
        int g = tid >> 2, w = tid & 3;
        ((float*)bias4)[tid] = sel4(g, bf, bi, bu, bo)[w] + sel4(g, thf, thi, thu, tho)[w];
    }
    __syncthreads();

    size_t r = (size_t)blockIdx.x * 256 + tid;          // row in [0, T*B)
    const float4* xr = (const float4*)(x + r * 32);
    float4 xv[8];
#pragma unroll
    for (int k = 0; k < 8; ++k) xv[k] = xr[k];

    float4 acc[4];
#pragma unroll
    for (int q = 0; q < 4; ++q) acc[q] = bias4[q];

#pragma unroll
    for (int j = 0; j < 32; ++j) {
        float xj = ((const float*)xv)[j];
#pragma unroll
        for (int q = 0; q < 4; ++q) {
            float4 wv = Wl[j][q];
            acc[q].x = fmaf(xj, wv.x, acc[q].x);
            acc[q].y = fmaf(xj, wv.y, acc[q].y);
            acc[q].z = fmaf(xj, wv.z, acc[q].z);
            acc[q].w = fmaf(xj, wv.w, acc[q].w);
        }
    }

    union { __half2 h2; unsigned u; } cv;
    uint4 s0, s1;
    cv.h2 = __floats2half2_rn(acc[0].x, acc[0].y); s0.x = cv.u;
    cv.h2 = __floats2half2_rn(acc[0].z, acc[0].w); s0.y = cv.u;
    cv.h2 = __floats2half2_rn(acc[1].x, acc[1].y); s0.z = cv.u;
    cv.h2 = __floats2half2_rn(acc[1].z, acc[1].w); s0.w = cv.u;
    cv.h2 = __floats2half2_rn(acc[2].x, acc[2].y); s1.x = cv.u;
    cv.h2 = __floats2half2_rn(acc[2].z, acc[2].w); s1.y = cv.u;
    cv.h2 = __floats2half2_rn(acc[3].x, acc[3].y); s1.z = cv.u;
    cv.h2 = __floats2half2_rn(acc[3].z, acc[3].w); s1.w = cv.u;
    uint4* Ap = (uint4*)Ax + r * 2;
    Ap[0] = s0; Ap[1] = s1;
}

// ---------------- Phase 2: sequential scan, 4 lanes per batch row (lane = gate) -------------
// __launch_bounds__(64, 1): only 256 waves exist chip-wide (1 wave/CU), so target
// 1 wave/EU occupancy -> allocator may use the full VGPR file instead of
// rematerializing wh/bias via per-step global reloads (r2: VGPR_Count=28 smoking gun).
template<int FUSED>
__global__ __launch_bounds__(64, 1) void qlstm_scan(
    const __half* __restrict__ Ax, const float* __restrict__ x,
    const float* __restrict__ Wf, const float* __restrict__ bf, const float* __restrict__ thf,
    const float* __restrict__ Wi, const float* __restrict__ bi, const float* __restrict__ thi,
    const float* __restrict__ Wu, const float* __restrict__ bu, const float* __restrict__ thu,
    const float* __restrict__ Wo, const float* __restrict__ bo, const float* __restrict__ tho,
    float* __restrict__ out)
{
    int lane = threadIdx.x;                 // 0..63, one wave per block
    int gid  = blockIdx.x * 64 + lane;      // 0..16383
    int b    = gid >> 2;                    // batch row
    int g    = lane & 3;                    // gate: 0=f 1=i 2=u 3=o

    const float* Wg = sel4(g, Wf, Wi, Wu, Wo);
    float wh[4][4];                         // recurrent weights Wh[j][w] = Wg[(32+j)*4+w]
#pragma unroll
    for (int j = 0; j < 4; ++j)
#pragma unroll
        for (int w = 0; w < 4; ++w)
            wh[j][w] = Wg[(32 + j) * 4 + w];

    __shared__ float4 Wl[32][4];
    float bias[4] = {0, 0, 0, 0};
    if (FUSED) {
        for (int idx = lane; idx < 512; idx += 64) {
            int j = idx >> 4, c = idx & 15, gg = c >> 2, w = c & 3;
            ((float*)Wl)[idx] = sel4(gg, Wf, Wi, Wu, Wo)[j * 4 + w];
        }
#pragma unroll
        for (int w = 0; w < 4; ++w)
            bias[w] = sel4(g, bf, bi, bu, bo)[w] + sel4(g, thf, thi, thu, tho)[w];
        __syncthreads();
    }

    float hx[4] = {0, 0, 0, 0}, cx[4] = {0, 0, 0, 0};

    const uint2* Axp = (const uint2*)Ax + (size_t)b * 4 + g;  // +t*16384 per step
    const float4* xp = (const float4*)x + (size_t)b * 8;      // +t*32768 per step

    uint2 buf[PD];
    float4 xnxt[8];
    if (!FUSED) {
#pragma unroll
        for (int k = 0; k < PD; ++k) buf[k] = Axp[(size_t)k * (BB * 4)];
    } else {
#pragma unroll
        for (int k = 0; k < 8; ++k) xnxt[k] = xp[k];
    }

#pragma unroll PD
    for (int t = 0; t < TT; ++t) {
        float ax[4];
        if (!FUSED) {
            uint2 cur = buf[t % PD];                       // static after unroll-by-PD
            if (t + PD < TT) buf[t % PD] = Axp[(size_t)(t + PD) * (BB * 4)];
            __half2 p0 = *reinterpret_cast<const __half2*>(&cur.x);
            __half2 p1 = *reinterpret_cast<const __half2*>(&cur.y);
            float2 f0 = __half22float2(p0), f1 = __half22float2(p1);
            ax[0] = f0.x; ax[1] = f0.y; ax[2] = f1.x; ax[3] = f1.y;
        } else {
            float4 xc[8];
#pragma unroll
            for (int k = 0; k < 8; ++k) xc[k] = xnxt[k];
            if (t + 1 < TT) {
#pragma unroll
                for (int k = 0; k < 8; ++k) xnxt[k] = xp[(size_t)(t + 1) * (BB * 8) + k];
            }
#pragma unroll
            for (int w = 0; w < 4; ++w) ax[w] = bias[w];
#pragma unroll
            for (int j = 0; j < 32; ++j) {
                float xj = ((const float*)xc)[j];
                float4 wv = Wl[j][g];
                ax[0] = fmaf(xj, wv.x, ax[0]);
                ax[1] = fmaf(xj, wv.y, ax[1]);
                ax[2] = fmaf(xj, wv.z, ax[2]);
                ax[3] = fmaf(xj, wv.w, ax[3]);
            }
        }

        // angles -> cos
        float C[4];
#pragma unroll
        for (int w = 0; w < 4; ++w) {
            float a = ax[w];
            a = fmaf(hx[0], wh[0][w], a);
            a = fmaf(hx[1], wh[1][w], a);
            a = fmaf(hx[2], wh[2][w], a);
            a = fmaf(hx[3], wh[3][w], a);
            C[w] = __cosf(a);
        }
        // z via XOR-subset products (closed form of CNOT ring + PauliZ)
        float t12 = C[1] * C[2];
        float z[4];
        z[1] = C[0] * C[1];
        z[2] = C[0] * t12;
        z[0] = t12 * C[3];
        z[3] = z[2] * C[3];

        bool isU = (g == 2);
        float act[4];
#pragma unroll
        for (int w = 0; w < 4; ++w) {
            float zz = isU ? z[w] + z[w] : z[w];
            float y = sigmoid_fast(zz);                 // tanh(x) = 2*sigmoid(2x)-1
            act[w] = isU ? fmaf(2.0f, y, -1.0f) : y;
        }

        // quad gather via DPP quad_perm broadcasts (VALU-speed, no LDS)
        float hxn[4], cxn[4];
#pragma unroll
        for (int w = 0; w < 4; ++w) {
            float fw = quad_bcast<0x00>(act[w]);   // lane base4+0
            float iw = quad_bcast<0x55>(act[w]);   // lane base4+1
            float uw = quad_bcast<0xAA>(act[w]);   // lane base4+2
            float ow = quad_bcast<0xFF>(act[w]);   // lane base4+3
            float c2 = fmaf(fw, cx[w], iw * uw);
            float th = tanh_fast(c2);
            cxn[w] = c2;
            hxn[w] = ow * th;
        }
#pragma unroll
        for (int w = 0; w < 4; ++w) { hx[w] = hxn[w]; cx[w] = cxn[w]; }

        float o01 = (g & 1) ? hx[1] : hx[0];
        float o23 = (g & 1) ? hx[3] : hx[2];
        out[(size_t)t * 16384 + gid] = (g & 2) ? o23 : o01;
    }

    // final (hx, cx)
    {
        float o01 = (g & 1) ? hx[1] : hx[0];
        float o23 = (g & 1) ? hx[3] : hx[2];
        out[(size_t)TT * 16384 + gid] = (g & 2) ? o23 : o01;
        float c01 = (g & 1) ? cx[1] : cx[0];
        float c23 = (g & 1) ? cx[3] : cx[2];
        out[(size_t)TT * 16384 + 16384 + gid] = (g & 2) ? c23 : c01;
    }
}

extern "C" void kernel_launch(void* const* d_in, const int* in_sizes, int n_in,
                              void* d_out, int out_size, void* d_ws, size_t ws_size,
                              hipStream_t stream) {
    const float* x   = (const float*)d_in[0];
    const float* Wf  = (const float*)d_in[1];
    const float* bf  = (const float*)d_in[2];
    const float* thf = (const float*)d_in[3];
    const float* Wi  = (const float*)d_in[4];
    const float* bi  = (const float*)d_in[5];
    const float* thi = (const float*)d_in[6];
    const float* Wu  = (const float*)d_in[7];
    const float* bu  = (const float*)d_in[8];
    const float* thu = (const float*)d_in[9];
    const float* Wo  = (const float*)d_in[10];
    const float* bo  = (const float*)d_in[11];
    const float* tho = (const float*)d_in[12];
    float* out = (float*)d_out;

    size_t need = (size_t)TT * BB * 16 * sizeof(__half);   // 64 MB
    if (ws_size >= need) {
        __half* Ax = (__half*)d_ws;
        qlstm_pre<<<(TT * BB) / 256, 256, 0, stream>>>(
            x, Wf, bf, thf, Wi, bi, thi, Wu, bu, thu, Wo, bo, tho, Ax);
        qlstm_scan<0><<<(BB * 4) / 64, 64, 0, stream>>>(
            Ax, x, Wf, bf, thf, Wi, bi, thi, Wu, bu, thu, Wo, bo, tho, out);
    } else {
        qlstm_scan<1><<<(BB * 4) / 64, 64, 0, stream>>>(
            nullptr, x, Wf, bf, thf, Wi, bi, thi, Wu, bu, thu, Wo, bo, tho, out);
    }
}

// Round 4
// 207.946 us; speedup vs baseline: 1.4062x; 1.0731x over previous
//
#include <hip/hip_runtime.h>
#include <hip/hip_fp16.h>

#define TT 512
#define BB 4096
#define PD 8   // prefetch depth; TT % PD == 0; inner loop trip count (always unrolled)

__device__ __forceinline__ const float* sel4(int g, const float* a, const float* b,
                                             const float* c, const float* d) {
    return g == 0 ? a : (g == 1 ? b : (g == 2 ? c : d));
}

__device__ __forceinline__ float sigmoid_fast(float x) {
    float e = __expf(-x);
    return __builtin_amdgcn_rcpf(1.0f + e);
}
__device__ __forceinline__ float tanh_fast(float x) {
    float e = __expf(-2.0f * x);
    return fmaf(2.0f, __builtin_amdgcn_rcpf(1.0f + e), -1.0f);
}

// DPP quad broadcast: every lane gets value from lane (quad_base + K) of its quad.
template<int CTRL>
__device__ __forceinline__ float quad_bcast(float v) {
    int i = __builtin_amdgcn_mov_dpp(__float_as_int(v), CTRL, 0xf, 0xf, true);
    return __int_as_float(i);
}

// ---------------- Phase 1: Ax[t*B+b][16] = x @ Wx + (b + theta), stored fp16 ----------------
// x staged through LDS so global loads are fully coalesced (lane-contiguous float4),
// LDS row pad = 33 floats -> conflict-free reads ((t + j) % 32 covers all banks, 2 lanes/bank).
__global__ __launch_bounds__(256) void qlstm_pre(
    const float* __restrict__ x,
    const float* __restrict__ Wf, const float* __restrict__ bf, const float* __restrict__ thf,
    const float* __restrict__ Wi, const float* __restrict__ bi, const float* __restrict__ thi,
    const float* __restrict__ Wu, const float* __restrict__ bu, const float* __restrict__ thu,
    const float* __restrict__ Wo, const float* __restrict__ bo, const float* __restrict__ tho,
    __half* __restrict__ Ax)
{
    __shared__ float4 Wl[32][4];   // Wl[j][q] = cols 4q..4q+3 of concatenated Wx at input j
    __shared__ float4 bias4[4];
    __shared__ float xs[256 * 33];
    int tid = threadIdx.x;
    for (int idx = tid; idx < 512; idx += 256) {
        int j = idx >> 4, c = idx & 15, g = c >> 2, w = c & 3;
        ((float*)Wl)[idx] = sel4(g, Wf, Wi, Wu, Wo)[j * 4 + w];
    }
    if (tid < 16) {
        int g = tid >> 2, w = tid & 3;
        ((float*)bias4)[tid] = sel4(g, bf, bi, bu, bo)[w] + sel4(g, thf, thi, thu, tho)[w];
    }

    size_t rbase = (size_t)blockIdx.x * 256;
    const float4* xg = (const float4*)(x + rbase * 32);
#pragma unroll
    for (int it = 0; it < 8; ++it) {
        int i = it * 256 + tid;                 // flat float4 index, coalesced
        float4 v = xg[i];
        int r = i >> 3, c = (i & 7) * 4;
        float* p = &xs[r * 33 + c];
        p[0] = v.x; p[1] = v.y; p[2] = v.z; p[3] = v.w;
    }
    __syncthreads();

    float4 acc[4];
#pragma unroll
    for (int q = 0; q < 4; ++q) acc[q] = bias4[q];

    const float* xr = &xs[tid * 33];
#pragma unroll
    for (int j = 0; j < 32; ++j) {
        float xj = xr[j];
#pragma unroll
        for (int q = 0; q < 4; ++q) {
            float4 wv = Wl[j][q];
            acc[q].x = fmaf(xj, wv.x, acc[q].x);
            acc[q].y = fmaf(xj, wv.y, acc[q].y);
            acc[q].z = fmaf(xj, wv.z, acc[q].z);
            acc[q].w = fmaf(xj, wv.w, acc[q].w);
        }
    }

    union { __half2 h2; unsigned u; } cv;
    uint4 s0, s1;
    cv.h2 = __floats2half2_rn(acc[0].x, acc[0].y); s0.x = cv.u;
    cv.h2 = __floats2half2_rn(acc[0].z, acc[0].w); s0.y = cv.u;
    cv.h2 = __floats2half2_rn(acc[1].x, acc[1].y); s0.z = cv.u;
    cv.h2 = __floats2half2_rn(acc[1].z, acc[1].w); s0.w = cv.u;
    cv.h2 = __floats2half2_rn(acc[2].x, acc[2].y); s1.x = cv.u;
    cv.h2 = __floats2half2_rn(acc[2].z, acc[2].w); s1.y = cv.u;
    cv.h2 = __floats2half2_rn(acc[3].x, acc[3].y); s1.z = cv.u;
    cv.h2 = __floats2half2_rn(acc[3].z, acc[3].w); s1.w = cv.u;
    uint4* Ap = (uint4*)Ax + (rbase + tid) * 2;
    Ap[0] = s0; Ap[1] = s1;
}

// ---------------- Phase 2: sequential scan, 4 lanes per batch row (lane = gate) -------------
// Chunked prefetch: outer loop over TT/PD chunks (NOT unrolled), inner #pragma unroll over
// k<PD (always fully unrolled) so buf[k] is compile-time-static -> stays in VGPRs (rule #20).
template<int FUSED>
__global__ __launch_bounds__(64, 1) void qlstm_scan(
    const __half* __restrict__ Ax, const float* __restrict__ x,
    const float* __restrict__ Wf, const float* __restrict__ bf, const float* __restrict__ thf,
    const float* __restrict__ Wi, const float* __restrict__ bi, const float* __restrict__ thi,
    const float* __restrict__ Wu, const float* __restrict__ bu, const float* __restrict__ thu,
    const float* __restrict__ Wo, const float* __restrict__ bo, const float* __restrict__ tho,
    float* __restrict__ out)
{
    int lane = threadIdx.x;                 // 0..63, one wave per block
    int gid  = blockIdx.x * 64 + lane;      // 0..16383
    int b    = gid >> 2;                    // batch row
    int g    = lane & 3;                    // gate: 0=f 1=i 2=u 3=o

    const float* Wg = sel4(g, Wf, Wi, Wu, Wo);
    float wh[4][4];                         // recurrent weights Wh[j][w] = Wg[(32+j)*4+w]
#pragma unroll
    for (int j = 0; j < 4; ++j)
#pragma unroll
        for (int w = 0; w < 4; ++w)
            wh[j][w] = Wg[(32 + j) * 4 + w];

    float hx[4] = {0, 0, 0, 0}, cx[4] = {0, 0, 0, 0};
    float* outp = out + gid;

    const uint2* Axp = (const uint2*)Ax + (size_t)b * 4 + g;  // +t*16384 per step

#define STEP_MATH()                                                            \
    do {                                                                       \
        float C[4];                                                            \
        _Pragma("unroll")                                                      \
        for (int w = 0; w < 4; ++w) {                                          \
            float a0 = fmaf(hx[0], wh[0][w], ax[w]);                           \
            float a1 = fmaf(hx[2], wh[2][w], hx[1] * wh[1][w]);                \
            a0 = fmaf(hx[3], wh[3][w], a0);                                    \
            C[w] = __cosf(a0 + a1);                                            \
        }                                                                      \
        float t12 = C[1] * C[2];                                               \
        float z[4];                                                            \
        z[1] = C[0] * C[1];                                                    \
        z[2] = C[0] * t12;                                                     \
        z[0] = t12 * C[3];                                                     \
        z[3] = z[2] * C[3];                                                    \
        bool isU = (g == 2);                                                   \
        float act[4];                                                          \
        _Pragma("unroll")                                                      \
        for (int w = 0; w < 4; ++w) {                                          \
            float zz = isU ? z[w] + z[w] : z[w];                               \
            float y = sigmoid_fast(zz);                                        \
            act[w] = isU ? fmaf(2.0f, y, -1.0f) : y;                           \
        }                                                                      \
        _Pragma("unroll")                                                      \
        for (int w = 0; w < 4; ++w) {                                          \
            float fw = quad_bcast<0x00>(act[w]);                               \
            float iw = quad_bcast<0x55>(act[w]);                               \
            float uw = quad_bcast<0xAA>(act[w]);                               \
            float ow = quad_bcast<0xFF>(act[w]);                               \
            float c2 = fmaf(fw, cx[w], iw * uw);                               \
            float th = tanh_fast(c2);                                          \
            cx[w] = c2;                                                        \
            hx[w] = ow * th;                                                   \
        }                                                                      \
        float o01 = (g & 1) ? hx[1] : hx[0];                                   \
        float o23 = (g & 1) ? hx[3] : hx[2];                                   \
        outp[(size_t)t_ * 16384] = (g & 2) ? o23 : o01;                        \
    } while (0)

    if (!FUSED) {
        uint2 buf[PD];
#pragma unroll
        for (int k = 0; k < PD; ++k) buf[k] = Axp[(size_t)k * (BB * 4)];

        for (int tc = 0; tc < TT; tc += PD) {        // 64 chunks, not unrolled
#pragma unroll
            for (int k = 0; k < PD; ++k) {           // trip 8: fully unrolled, buf[k] static
                int t_ = tc + k;
                uint2 cur = buf[k];
                int tn = (t_ + PD < TT) ? (t_ + PD) : (TT - 1);
                buf[k] = Axp[(size_t)tn * (BB * 4)]; // 8-deep in-flight window
                __half2 p0 = *reinterpret_cast<const __half2*>(&cur.x);
                __half2 p1 = *reinterpret_cast<const __half2*>(&cur.y);
                float2 f0 = __half22float2(p0), f1 = __half22float2(p1);
                float ax[4] = {f0.x, f0.y, f1.x, f1.y};
                STEP_MATH();
            }
        }
    } else {
        // Fallback: recompute x@W per step (no workspace). Correctness path only.
        __shared__ float4 Wl[32][4];
        float bias[4];
        for (int idx = lane; idx < 512; idx += 64) {
            int j = idx >> 4, c = idx & 15, gg = c >> 2, w = c & 3;
            ((float*)Wl)[idx] = sel4(gg, Wf, Wi, Wu, Wo)[j * 4 + w];
        }
#pragma unroll
        for (int w = 0; w < 4; ++w)
            bias[w] = sel4(g, bf, bi, bu, bo)[w] + sel4(g, thf, thi, thu, tho)[w];
        __syncthreads();

        const float4* xp = (const float4*)x + (size_t)b * 8;  // +t*32768 per step
        for (int t_ = 0; t_ < TT; ++t_) {
            float4 xc[8];
#pragma unroll
            for (int k = 0; k < 8; ++k) xc[k] = xp[(size_t)t_ * (BB * 8) + k];
            float ax[4];
#pragma unroll
            for (int w = 0; w < 4; ++w) ax[w] = bias[w];
#pragma unroll
            for (int j = 0; j < 32; ++j) {
                float xj = ((const float*)xc)[j];
                float4 wv = Wl[j][g];
                ax[0] = fmaf(xj, wv.x, ax[0]);
                ax[1] = fmaf(xj, wv.y, ax[1]);
                ax[2] = fmaf(xj, wv.z, ax[2]);
                ax[3] = fmaf(xj, wv.w, ax[3]);
            }
            STEP_MATH();
        }
    }

    // final (hx, cx)
    {
        float o01 = (g & 1) ? hx[1] : hx[0];
        float o23 = (g & 1) ? hx[3] : hx[2];
        out[(size_t)TT * 16384 + gid] = (g & 2) ? o23 : o01;
        float c01 = (g & 1) ? cx[1] : cx[0];
        float c23 = (g & 1) ? cx[3] : cx[2];
        out[(size_t)TT * 16384 + 16384 + gid] = (g & 2) ? c23 : c01;
    }
}

extern "C" void kernel_launch(void* const* d_in, const int* in_sizes, int n_in,
                              void* d_out, int out_size, void* d_ws, size_t ws_size,
                              hipStream_t stream) {
    const float* x   = (const float*)d_in[0];
    const float* Wf  = (const float*)d_in[1];
    const float* bf  = (const float*)d_in[2];
    const float* thf = (const float*)d_in[3];
    const float* Wi  = (const float*)d_in[4];
    const float* bi  = (const float*)d_in[5];
    const float* thi = (const float*)d_in[6];
    const float* Wu  = (const float*)d_in[7];
    const float* bu  = (const float*)d_in[8];
    const float* thu = (const float*)d_in[9];
    const float* Wo  = (const float*)d_in[10];
    const float* bo  = (const float*)d_in[11];
    const float* tho = (const float*)d_in[12];
    float* out = (float*)d_out;

    size_t need = (size_t)TT * BB * 16 * sizeof(__half);   // 64 MB
    if (ws_size >= need) {
        __half* Ax = (__half*)d_ws;
        qlstm_pre<<<(TT * BB) / 256, 256, 0, stream>>>(
            x, Wf, bf, thf, Wi, bi, thi, Wu, bu, thu, Wo, bo, tho, Ax);
        qlstm_scan<0><<<(BB * 4) / 64, 64, 0, stream>>>(
            Ax, x, Wf, bf, thf, Wi, bi, thi, Wu, bu, thu, Wo, bo, tho, out);
    } else {
        qlstm_scan<1><<<(BB * 4) / 64, 64, 0, stream>>>(
            nullptr, x, Wf, bf, thf, Wi, bi, thi, Wu, bu, thu, Wo, bo, tho, out);
    }
}

// Round 5
// 141.294 us; speedup vs baseline: 2.0696x; 1.4717x over previous
//
#include <hip/hip_runtime.h>
#include <hip/hip_fp16.h>

#define TT 512
#define BB 4096
#define PD 8   // prefetch depth; TT % PD == 0; inner loop fully unrolled -> buf[] static

__device__ __forceinline__ const float* sel4(int g, const float* a, const float* b,
                                             const float* c, const float* d) {
    return g == 0 ? a : (g == 1 ? b : (g == 2 ? c : d));
}

__device__ __forceinline__ float sigmoid_fast(float x) {
    float e = __expf(-x);
    return __builtin_amdgcn_rcpf(1.0f + e);
}
__device__ __forceinline__ float tanh_fast(float x) {
    float e = __expf(-2.0f * x);
    return fmaf(2.0f, __builtin_amdgcn_rcpf(1.0f + e), -1.0f);
}

// DPP move: arbitrary dpp_ctrl (quad_perm 0x00-0xFF, row_ror 0x120+N)
template<int CTRL>
__device__ __forceinline__ float dppf(float v) {
    int i = __builtin_amdgcn_mov_dpp(__float_as_int(v), CTRL, 0xf, 0xf, true);
    return __int_as_float(i);
}
#define QP(a,b,c,d) ((a) | ((b) << 2) | ((c) << 4) | ((d) << 6))
template<int CTRL>
__device__ __forceinline__ float quad_bcast(float v) { return dppf<CTRL>(v); }  // fallback use

// ---------------- Phase 1: Ax[t*B+b][16] = x @ Wx + (b + theta), stored fp16 ----------------
__global__ __launch_bounds__(256) void qlstm_pre(
    const float* __restrict__ x,
    const float* __restrict__ Wf, const float* __restrict__ bf, const float* __restrict__ thf,
    const float* __restrict__ Wi, const float* __restrict__ bi, const float* __restrict__ thi,
    const float* __restrict__ Wu, const float* __restrict__ bu, const float* __restrict__ thu,
    const float* __restrict__ Wo, const float* __restrict__ bo, const float* __restrict__ tho,
    __half* __restrict__ Ax)
{
    __shared__ float4 Wl[32][4];
    __shared__ float4 bias4[4];
    __shared__ float xs[256 * 33];
    int tid = threadIdx.x;
    for (int idx = tid; idx < 512; idx += 256) {
        int j = idx >> 4, c = idx & 15, g = c >> 2, w = c & 3;
        ((float*)Wl)[idx] = sel4(g, Wf, Wi, Wu, Wo)[j * 4 + w];
    }
    if (tid < 16) {
        int g = tid >> 2, w = tid & 3;
        ((float*)bias4)[tid] = sel4(g, bf, bi, bu, bo)[w] + sel4(g, thf, thi, thu, tho)[w];
    }

    size_t rbase = (size_t)blockIdx.x * 256;
    const float4* xg = (const float4*)(x + rbase * 32);
#pragma unroll
    for (int it = 0; it < 8; ++it) {
        int i = it * 256 + tid;
        float4 v = xg[i];
        int r = i >> 3, c = (i & 7) * 4;
        float* p = &xs[r * 33 + c];
        p[0] = v.x; p[1] = v.y; p[2] = v.z; p[3] = v.w;
    }
    __syncthreads();

    float4 acc[4];
#pragma unroll
    for (int q = 0; q < 4; ++q) acc[q] = bias4[q];

    const float* xr = &xs[tid * 33];
#pragma unroll
    for (int j = 0; j < 32; ++j) {
        float xj = xr[j];
#pragma unroll
        for (int q = 0; q < 4; ++q) {
            float4 wv = Wl[j][q];
            acc[q].x = fmaf(xj, wv.x, acc[q].x);
            acc[q].y = fmaf(xj, wv.y, acc[q].y);
            acc[q].z = fmaf(xj, wv.z, acc[q].z);
            acc[q].w = fmaf(xj, wv.w, acc[q].w);
        }
    }

    union { __half2 h2; unsigned u; } cv;
    uint4 s0, s1;
    cv.h2 = __floats2half2_rn(acc[0].x, acc[0].y); s0.x = cv.u;
    cv.h2 = __floats2half2_rn(acc[0].z, acc[0].w); s0.y = cv.u;
    cv.h2 = __floats2half2_rn(acc[1].x, acc[1].y); s0.z = cv.u;
    cv.h2 = __floats2half2_rn(acc[1].z, acc[1].w); s0.w = cv.u;
    cv.h2 = __floats2half2_rn(acc[2].x, acc[2].y); s1.x = cv.u;
    cv.h2 = __floats2half2_rn(acc[2].z, acc[2].w); s1.y = cv.u;
    cv.h2 = __floats2half2_rn(acc[3].x, acc[3].y); s1.z = cv.u;
    cv.h2 = __floats2half2_rn(acc[3].z, acc[3].w); s1.w = cv.u;
    uint4* Ap = (uint4*)Ax + (rbase + tid) * 2;
    Ap[0] = s0; Ap[1] = s1;
}

// ---------------- Phase 2: scan, 16 lanes per batch row (lane = gate*4 + wire) --------------
// 65536 lanes -> 1024 waves -> all 4 SIMDs of every CU busy (r4 had 1/4).
// All cross-lane traffic is DPP: quad_perm for wire products + hx gather (quad = one gate's
// 4 wires), row_ror 4/8/12 for the gate gather (runtime direction probe disambiguates ror).
__global__ __launch_bounds__(256) void qlstm_scan16(
    const __half* __restrict__ Ax,
    const float* __restrict__ Wf, const float* __restrict__ Wi,
    const float* __restrict__ Wu, const float* __restrict__ Wo,
    float* __restrict__ out)
{
    int tid = threadIdx.x;
    int gid = blockIdx.x * 256 + tid;   // 0..65535
    int b   = gid >> 4;                 // batch row
    int L   = gid & 15;
    int w   = L & 3;                    // wire (quad lane)
    int g   = L >> 2;                   // gate: 0=f 1=i 2=u 3=o

    const float* Wg = sel4(g, Wf, Wi, Wu, Wo);
    // recurrent weights keyed by xor-partner: term hx_{w^k} * Wh[w^k][w]
    float whA = Wg[(32 + w) * 4 + w];
    float whB = Wg[(32 + (w ^ 1)) * 4 + w];
    float whC = Wg[(32 + (w ^ 2)) * 4 + w];
    float whD = Wg[(32 + (w ^ 3)) * 4 + w];
    bool isU = (g == 2);
    bool wb0 = (w & 1) != 0, wb1 = (w & 2) != 0;

    // row_ror direction probe (one-time): is ror4 lane<-lane+4 (g+1) or lane-4 (g+3)?
    float probe = (float)g;
    bool rorPlus = (dppf<0x124>(probe) == (float)((g + 1) & 3));

    const __half* Axp = Ax + (size_t)b * 16 + L;
    float* outp = out + (size_t)b * 4 + w;

    float hx = 0.f, cx = 0.f;
    __half buf[PD];
#pragma unroll
    for (int k = 0; k < PD; ++k) buf[k] = Axp[(size_t)k * (BB * 16)];

    for (int tc = 0; tc < TT; tc += PD) {    // 64 chunks, not unrolled
#pragma unroll
        for (int k = 0; k < PD; ++k) {       // fully unrolled: buf[k] static
            int t = tc + k;
            float ax = __half2float(buf[k]);
            int tn = (t + PD < TT) ? t + PD : TT - 1;
            buf[k] = Axp[(size_t)tn * (BB * 16)];

            // angle = ax + sum_j hx_j * Wh[j][w]  (hx_j via quad xor perms)
            float h1 = dppf<QP(1, 0, 3, 2)>(hx);   // hx_{w^1}
            float h2 = dppf<QP(2, 3, 0, 1)>(hx);   // hx_{w^2}
            float h3 = dppf<QP(3, 2, 1, 0)>(hx);   // hx_{w^3}
            float a = fmaf(hx, whA, ax);
            a = fmaf(h1, whB, a);
            a = fmaf(h2, whC, a);
            a = fmaf(h3, whD, a);
            float C = __cosf(a);

            // z products: z0=C1C2C3 z1=C0C1 z2=C0C1C2 z3=C0C1C2C3 (xor-style, direction-free)
            float Cx1 = dppf<QP(1, 0, 3, 2)>(C);          // C_{w^1}
            float P   = C * Cx1;                           // pair product
            float Px2 = dppf<QP(2, 3, 0, 1)>(P);           // other pair's product
            float Q   = P * Px2;                           // full product
            float m   = wb1 ? C : Cx1;                     // w2: *C2 ; w0: *C1
            float T   = Px2 * m;                           // w0: C1C2C3 ; w2: C0C1C2
            float z   = wb0 ? (wb1 ? Q : P) : T;

            // activations: sigma poly (|z|<=1, err~2e-4); tanh Pade[3/2] (err~3e-4)
            float z2 = z * z;
            float sig = fmaf(z, fmaf(z2, fmaf(z2, 0.00208333f, -0.0208333f), 0.25f), 0.5f);
            float tp  = (z * (15.0f + z2)) * __builtin_amdgcn_rcpf(fmaf(6.0f, z2, 15.0f));
            float act = isU ? tp : sig;

            // gate gather: need act(0..3) at fixed wire; row_ror 4/8/12 + masked selects
            float ra = dppf<0x124>(act);   // act(g+-1)
            float rb = dppf<0x128>(act);   // act(g+2)  (rot2 == xor2: direction-free)
            float rc = dppf<0x12C>(act);   // act(g-+1)
            float r1 = rorPlus ? ra : rc;  // act(g+1)
            float r3 = rorPlus ? rc : ra;  // act(g+3)
            float f = (g == 0) ? act : (g == 1) ? r3 : (g == 2) ? rb : r1;
            float i = (g == 0) ? r1 : (g == 1) ? act : (g == 2) ? r3 : rb;
            float u = (g == 0) ? rb : (g == 1) ? r1 : (g == 2) ? act : r3;
            float o = (g == 0) ? r3 : (g == 1) ? rb : (g == 2) ? r1 : act;

            float c2 = fmaf(f, cx, i * u);
            cx = c2;
            float th = tanh_fast(c2);
            hx = o * th;

            // all 4 g-lanes hold identical hx -> same-address dup store (benign, same value)
            outp[(size_t)t * 16384] = hx;
        }
    }
    outp[(size_t)TT * 16384] = hx;
    outp[(size_t)TT * 16384 + 16384] = cx;
}

// ---------------- Fallback (no workspace): 4 lanes/row, recompute x@W per step --------------
__global__ __launch_bounds__(64, 1) void qlstm_scan_fb(
    const float* __restrict__ x,
    const float* __restrict__ Wf, const float* __restrict__ bf, const float* __restrict__ thf,
    const float* __restrict__ Wi, const float* __restrict__ bi, const float* __restrict__ thi,
    const float* __restrict__ Wu, const float* __restrict__ bu, const float* __restrict__ thu,
    const float* __restrict__ Wo, const float* __restrict__ bo, const float* __restrict__ tho,
    float* __restrict__ out)
{
    int lane = threadIdx.x;
    int gid  = blockIdx.x * 64 + lane;
    int b    = gid >> 2;
    int g    = lane & 3;

    const float* Wg = sel4(g, Wf, Wi, Wu, Wo);
    float wh[4][4];
#pragma unroll
    for (int j = 0; j < 4; ++j)
#pragma unroll
        for (int w = 0; w < 4; ++w)
            wh[j][w] = Wg[(32 + j) * 4 + w];

    __shared__ float4 Wl[32][4];
    float bias[4];
    for (int idx = lane; idx < 512; idx += 64) {
        int j = idx >> 4, c = idx & 15, gg = c >> 2, w = c & 3;
        ((float*)Wl)[idx] = sel4(gg, Wf, Wi, Wu, Wo)[j * 4 + w];
    }
#pragma unroll
    for (int w = 0; w < 4; ++w)
        bias[w] = sel4(g, bf, bi, bu, bo)[w] + sel4(g, thf, thi, thu, tho)[w];
    __syncthreads();

    float hx[4] = {0, 0, 0, 0}, cx[4] = {0, 0, 0, 0};
    const float4* xp = (const float4*)x + (size_t)b * 8;

    for (int t = 0; t < TT; ++t) {
        float4 xc[8];
#pragma unroll
        for (int k = 0; k < 8; ++k) xc[k] = xp[(size_t)t * (BB * 8) + k];
        float ax[4];
#pragma unroll
        for (int w = 0; w < 4; ++w) ax[w] = bias[w];
#pragma unroll
        for (int j = 0; j < 32; ++j) {
            float xj = ((const float*)xc)[j];
            float4 wv = Wl[j][g];
            ax[0] = fmaf(xj, wv.x, ax[0]);
            ax[1] = fmaf(xj, wv.y, ax[1]);
            ax[2] = fmaf(xj, wv.z, ax[2]);
            ax[3] = fmaf(xj, wv.w, ax[3]);
        }
        float C[4];
#pragma unroll
        for (int w = 0; w < 4; ++w) {
            float a0 = fmaf(hx[0], wh[0][w], ax[w]);
            float a1 = fmaf(hx[2], wh[2][w], hx[1] * wh[1][w]);
            a0 = fmaf(hx[3], wh[3][w], a0);
            C[w] = __cosf(a0 + a1);
        }
        float t12 = C[1] * C[2];
        float z[4];
        z[1] = C[0] * C[1];
        z[2] = C[0] * t12;
        z[0] = t12 * C[3];
        z[3] = z[2] * C[3];
        bool isU = (g == 2);
        float act[4];
#pragma unroll
        for (int w = 0; w < 4; ++w) {
            float zz = isU ? z[w] + z[w] : z[w];
            float y = sigmoid_fast(zz);
            act[w] = isU ? fmaf(2.0f, y, -1.0f) : y;
        }
#pragma unroll
        for (int w = 0; w < 4; ++w) {
            float fw = quad_bcast<QP(0, 0, 0, 0)>(act[w]);
            float iw = quad_bcast<QP(1, 1, 1, 1)>(act[w]);
            float uw = quad_bcast<QP(2, 2, 2, 2)>(act[w]);
            float ow = quad_bcast<QP(3, 3, 3, 3)>(act[w]);
            float c2 = fmaf(fw, cx[w], iw * uw);
            cx[w] = c2;
            hx[w] = ow * tanh_fast(c2);
        }
        float o01 = (g & 1) ? hx[1] : hx[0];
        float o23 = (g & 1) ? hx[3] : hx[2];
        out[(size_t)t * 16384 + gid] = (g & 2) ? o23 : o01;
    }
    float o01 = (g & 1) ? hx[1] : hx[0];
    float o23 = (g & 1) ? hx[3] : hx[2];
    out[(size_t)TT * 16384 + gid] = (g & 2) ? o23 : o01;
    float c01 = (g & 1) ? cx[1] : cx[0];
    float c23 = (g & 1) ? cx[3] : cx[2];
    out[(size_t)TT * 16384 + 16384 + gid] = (g & 2) ? c23 : c01;
}

extern "C" void kernel_launch(void* const* d_in, const int* in_sizes, int n_in,
                              void* d_out, int out_size, void* d_ws, size_t ws_size,
                              hipStream_t stream) {
    const float* x   = (const float*)d_in[0];
    const float* Wf  = (const float*)d_in[1];
    const float* bf  = (const float*)d_in[2];
    const float* thf = (const float*)d_in[3];
    const float* Wi  = (const float*)d_in[4];
    const float* bi  = (const float*)d_in[5];
    const float* thi = (const float*)d_in[6];
    const float* Wu  = (const float*)d_in[7];
    const float* bu  = (const float*)d_in[8];
    const float* thu = (const float*)d_in[9];
    const float* Wo  = (const float*)d_in[10];
    const float* bo  = (const float*)d_in[11];
    const float* tho = (const float*)d_in[12];
    float* out = (float*)d_out;

    size_t need = (size_t)TT * BB * 16 * sizeof(__half);   // 64 MB
    if (ws_size >= need) {
        __half* Ax = (__half*)d_ws;
        qlstm_pre<<<(TT * BB) / 256, 256, 0, stream>>>(
            x, Wf, bf, thf, Wi, bi, thi, Wu, bu, thu, Wo, bo, tho, Ax);
        qlstm_scan16<<<(BB * 16) / 256, 256, 0, stream>>>(Ax, Wf, Wi, Wu, Wo, out);
    } else {
        qlstm_scan_fb<<<(BB * 4) / 64, 64, 0, stream>>>(
            x, Wf, bf, thf, Wi, bi, thi, Wu, bu, thu, Wo, bo, tho, out);
    }
}